// Round 11
// baseline (60.824 us; speedup 1.0000x reference)
//
#include <hip/hip_runtime.h>

// Problem constants (B=1): inputs (N=32768, D=1024) f32, tag_to_token (T=128, N) f32,
// gat_mask (T, T) i32. Output (T, D) f32.
#define NTOK 32768
#define NTAG 128
#define DDIM 1024
#define TPB 32  // tokens per fused block

// ws layout:
//   P   : 128*1024 f32 = 524288 B (unscaled per-tag sums)
//   cnt : 128 i32      = 512 B
//   RT  : 8*16*128 f32 = 65536 B  (16-row-group fused rows, row-major:
//                                  RT[(g*16+jj)*128 + t] = rtilde_{16g+jj}[t])

// ---------------------------------------------------------------------------
// Kernel 0 (k_rt): zero P/cnt + build fused-row table RT for 16-row groups.
// deduce_child(gm) == gm for ANY input (the reference inner loop is provably
// a no-op: rows j>i are still zero at outer step i). Block back-substitution:
//   rtilde_j = gm_j masked to t outside (j, 16g+16)
//            + sum_{k in group, k>j} gm_j[k] * rtilde_k
// so all 16 rows of a group are exact linear functionals of the SAME
// pre-group state (entries are exact small integers in f32).
// Grid 16 x 256: every block zeroes a P slice; blocks 0..7 build group b.
// ---------------------------------------------------------------------------
__global__ __launch_bounds__(256) void k_rt(const int* __restrict__ gm,
                                            float* __restrict__ P,
                                            int* __restrict__ cnt,
                                            float* __restrict__ RT) {
    __shared__ float rt[16][NTAG];
    __shared__ float gblk[16][16];
    const int tid = threadIdx.x;
    const int b = blockIdx.x;

    // Zero P: 32768 float4 over 4096 threads -> 8 each. Zero cnt (block 0).
    float4* P4 = reinterpret_cast<float4*>(P);
#pragma unroll
    for (int q = 0; q < 8; ++q)
        P4[q * 4096 + b * 256 + tid] = make_float4(0.f, 0.f, 0.f, 0.f);
    if (b == 0 && tid < NTAG) cnt[tid] = 0;

    if (b >= 8) return;
    const int g0 = b * 16;
    const int t = tid & 127;  // column (tids 128..255 are identical duplicates)

    // In-group 16x16 adjacency (one element per thread).
    gblk[tid >> 4][tid & 15] =
        (float)(gm[(g0 + (tid >> 4)) * NTAG + g0 + (tid & 15)] != 0);

    // This thread's column of the 16 base rows.
    float grows[16];
#pragma unroll
    for (int jj = 0; jj < 16; ++jj)
        grows[jj] = (float)(gm[(g0 + jj) * NTAG + t] != 0);
    __syncthreads();

#pragma unroll
    for (int jj = 15; jj >= 0; --jj) {
        const int j = g0 + jj;
        float acc = (t > j && t < g0 + 16) ? 0.f : grows[jj];
        for (int k = jj + 1; k < 16; ++k) acc += gblk[jj][k] * rt[k][t];
        rt[jj][t] = acc;  // duplicate tids write identical values: benign
        __syncthreads();
    }

#pragma unroll
    for (int jj = 0; jj < 16; ++jj) RT[(g0 + jj) * NTAG + t] = rt[jj][t];
}

// ---------------------------------------------------------------------------
// Kernel 1: fused tag-scan + segmented sum (unchanged since R6; ~15us by the
// R6 ledger). Math fact: deduce_direct_string's temp[i][n] is 1 iff i is the
// LAST covering tag of n (for ANY 0/1 coverage), so the row-normalized t2t
// is one-hot per token / cnt[tag] -> the big matmul is a segmented sum into
// P[tag], scaled later by 1/cnt.
// ---------------------------------------------------------------------------
__global__ __launch_bounds__(256) void k_fused(const float* __restrict__ inp,
                                               const float* __restrict__ t2t,
                                               float* __restrict__ P,
                                               int* __restrict__ cnt) {
    __shared__ int part[8][TPB];
    __shared__ int tags[TPB];
    const int tid = threadIdx.x;
    const int n0 = blockIdx.x * TPB;

    {
        const int c = tid >> 5;  // row chunk (16 rows)
        const int n = tid & 31;  // token within block
        int m = -1;
#pragma unroll
        for (int j = 0; j < 16; ++j) {
            const int r = c * 16 + j;
            if (t2t[(size_t)r * NTOK + n0 + n] > 0.f) m = r;
        }
        part[c][n] = m;
    }
    __syncthreads();
    if (tid < TPB) {
        int m = -1;
#pragma unroll
        for (int cc = 0; cc < 8; ++cc) m = max(m, part[cc][tid]);
        tags[tid] = m;
    }
    __syncthreads();

    const int col = tid * 4;
    const float4* src = reinterpret_cast<const float4*>(inp) + (size_t)n0 * 256 + tid;

    float4 acc = make_float4(0.f, 0.f, 0.f, 0.f);
    int cur = tags[0];
    int runlen = 0;

#pragma unroll
    for (int half = 0; half < 2; ++half) {
        float4 v[16];
#pragma unroll
        for (int k = 0; k < 16; ++k)
            v[k] = src[(size_t)(half * 16 + k) * 256];  // 16 loads in flight
#pragma unroll
        for (int k = 0; k < 16; ++k) {
            const int tg = tags[half * 16 + k];
            if (tg != cur) {  // wave-uniform (tags uniform across lanes)
                if (cur >= 0) {
                    float* p = P + (size_t)cur * DDIM + col;
                    atomicAdd(p + 0, acc.x);
                    atomicAdd(p + 1, acc.y);
                    atomicAdd(p + 2, acc.z);
                    atomicAdd(p + 3, acc.w);
                    if (tid == 0) atomicAdd(&cnt[cur], runlen);
                }
                acc = make_float4(0.f, 0.f, 0.f, 0.f);
                cur = tg;
                runlen = 0;
            }
            if (tg >= 0) {
                acc.x += v[k].x;
                acc.y += v[k].y;
                acc.z += v[k].z;
                acc.w += v[k].w;
                ++runlen;
            }
        }
    }
    if (cur >= 0) {
        float* p = P + (size_t)cur * DDIM + col;
        atomicAdd(p + 0, acc.x);
        atomicAdd(p + 1, acc.y);
        atomicAdd(p + 2, acc.z);
        atomicAdd(p + 3, acc.w);
        if (tid == 0) atomicAdd(&cnt[cur], runlen);
    }
}

// ---------------------------------------------------------------------------
// Kernel 2 (k_apply): recurrence apply with ZERO cross-lane operations.
// R7-R10's k_recur variants all carried 512 DPP reduction hops and all cost
// ~32us regardless of structure -> the cross-lane chain is the invariant
// cost. Here each group-step is a dense (16x128)x(128x64) mini-matmul:
// thread (j = tid>>4, c4 = tid&15) computes one row x float4-col dot of
// length 128 from LDS (RT row: uniform broadcast; o: 2-way/broadcast,
// conflict-free), then the 16 new rows are written back. 8 groups, 3
// barriers each. Per thread total: 4096 fma4 -> ~4-5us wall on 16 CUs.
// ---------------------------------------------------------------------------
__global__ __launch_bounds__(256) void k_apply(const float* __restrict__ P,
                                               const float* __restrict__ RT,
                                               const int* __restrict__ cnt,
                                               float* __restrict__ out) {
    __shared__ float o_lds[NTAG * 68];    // rows of 64 cols, stride 68 (16B-aligned)
    __shared__ float rt_g[16 * 132];      // one group's rows, stride 132 (bank-spread)
    const int tid = threadIdx.x;
    const int c0 = blockIdx.x * 64;

    // Load P rows (scaled by 1/cnt) into LDS: thread -> (row r, half h).
    {
        const int r = tid >> 1;
        const int h = tid & 1;
        const float inv = 1.0f / (float)cnt[r];
        const float4* src = reinterpret_cast<const float4*>(P + (size_t)r * DDIM + c0 + h * 32);
#pragma unroll
        for (int q = 0; q < 8; ++q) {
            float4 v = src[q];
            v.x *= inv; v.y *= inv; v.z *= inv; v.w *= inv;
            *reinterpret_cast<float4*>(&o_lds[r * 68 + h * 32 + q * 4]) = v;
        }
    }

    const int j = tid >> 4;   // row within group (0..15)
    const int c4 = tid & 15;  // float4 column (0..15)

    for (int g = 7; g >= 0; --g) {
        __syncthreads();  // o writes (or init load) visible; rt_g reusable
        // Stage group g's 16x128 RT rows (2048 floats / 256 thr = 8 each).
#pragma unroll
        for (int q = 0; q < 8; ++q) {
            const int i = q * 256 + tid;
            rt_g[(i >> 7) * 132 + (i & 127)] = RT[g * 16 * NTAG + i];
        }
        __syncthreads();

        const float* rrow = &rt_g[j * 132];
        float4 acc = make_float4(0.f, 0.f, 0.f, 0.f);
#pragma unroll 8
        for (int t = 0; t < NTAG; ++t) {
            const float w = rrow[t];
            const float4 ov = *reinterpret_cast<const float4*>(&o_lds[t * 68 + c4 * 4]);
            acc.x += w * ov.x;
            acc.y += w * ov.y;
            acc.z += w * ov.z;
            acc.w += w * ov.w;
        }
        __syncthreads();  // all dots done before overwriting group rows
        *reinterpret_cast<float4*>(&o_lds[(g * 16 + j) * 68 + c4 * 4]) = acc;
    }
    __syncthreads();

    // Store result, coalesced by rows.
    {
        const int r = tid >> 1;
        const int h = tid & 1;
        float4* dst = reinterpret_cast<float4*>(out + (size_t)r * DDIM + c0 + h * 32);
#pragma unroll
        for (int q = 0; q < 8; ++q)
            dst[q] = *reinterpret_cast<const float4*>(&o_lds[r * 68 + h * 32 + q * 4]);
    }
}

// ---------------------------------------------------------------------------
extern "C" void kernel_launch(void* const* d_in, const int* in_sizes, int n_in,
                              void* d_out, int out_size, void* d_ws, size_t ws_size,
                              hipStream_t stream) {
    const float* inp = (const float*)d_in[0];  // (N, D)
    const float* t2t = (const float*)d_in[1];  // (T, N)
    const int* gm = (const int*)d_in[2];       // (T, T)
    float* out = (float*)d_out;                // (T, D)

    char* ws = (char*)d_ws;
    float* P = (float*)ws;               // 524288 B
    int* cnt = (int*)(ws + 524288);      // 512 B
    float* RT = (float*)(ws + 524800);   // 65536 B

    k_rt<<<16, 256, 0, stream>>>(gm, P, cnt, RT);
    k_fused<<<NTOK / TPB, 256, 0, stream>>>(inp, t2t, P, cnt);
    k_apply<<<DDIM / 64, 256, 0, stream>>>(P, RT, cnt, out);
}